// Round 1
// baseline (450.629 us; speedup 1.0000x reference)
//
#include <hip/hip_runtime.h>
#include <hip/hip_bf16.h>
#include <stdint.h>

#define NPTS 8192
#define HIDDIM 64

typedef float f32x4 __attribute__((ext_vector_type(4)));
typedef short s16x8 __attribute__((ext_vector_type(8)));

// ---------- helpers ----------

// bf16 round-to-nearest-even
__device__ __forceinline__ unsigned short f2bf(float f) {
    unsigned int u = __builtin_bit_cast(unsigned int, f);
    u += 0x7FFFu + ((u >> 16) & 1u);
    return (unsigned short)(u >> 16);
}

// Y is stored in global memory pre-swizzled into MFMA B-fragment order:
// for element (k, col):  kblock = k>>5 (32 k's), c = col>>4, n = col&15,
// inner = (k&31) ^ ((col&3)<<3)   (XOR swizzle keeps ds_read_b128 bank-conflict-free)
__device__ __forceinline__ int yswz_idx(int k, int col) {
    return ((k >> 5) << 11) + ((col >> 4) << 9) + ((col & 15) << 5)
         + ((k & 31) ^ ((col & 3) << 3));
}

// ---------- kernel 1: mask floats (256 MiB) + packed mask bits + dinv ----------
// grid 512, block 256 (4 waves). wave handles 4 rows; lane = j within 64-chunk.
__global__ __launch_bounds__(256) void k_mask(const float* __restrict__ states,
                                              float* __restrict__ mout,
                                              unsigned long long* __restrict__ maskb,
                                              float* __restrict__ dinv) {
    int tid = threadIdx.x;
    int wv = tid >> 6, L = tid & 63;
    int rowbase = blockIdx.x * 16 + wv * 4;
    for (int rr = 0; rr < 4; ++rr) {
        int i = rowbase + rr;
        float xi = states[i * 4 + 0];
        float yi = states[i * 4 + 1];
        int deg = 0;
        float* orow = mout + (size_t)i * NPTS;
        unsigned long long* brow = maskb + (size_t)i * 128;
        for (int it = 0; it < 128; ++it) {
            int j = it * 64 + L;
            float xj = states[j * 4 + 0];
            float yj = states[j * 4 + 1];
            float dx = xi - xj;                    // single sub: exact per-op
            float dy = yi - yj;
            // MUST match numpy fp32 (dx*dx) + (dy*dy) with no FMA contraction:
            float d2 = __fadd_rn(__fmul_rn(dx, dx), __fmul_rn(dy, dy));
            bool pred = (d2 <= 1.0f);
            orow[j] = pred ? 1.0f : 0.0f;
            unsigned long long b = __ballot(pred);
            if (L == 0) brow[it] = b;
            deg += (int)__popcll(b);
        }
        if (L == 0) dinv[i] = rsqrtf((float)deg);
    }
}

// ---------- kernel 2: Y1 = dinv * (states @ W1), bf16 swizzled ----------
__global__ __launch_bounds__(256) void k_y1(const float* __restrict__ states,
                                            const float* __restrict__ W1,
                                            const float* __restrict__ dinv,
                                            unsigned short* __restrict__ yswz) {
    int gid = blockIdx.x * 256 + threadIdx.x;
    int col = gid & 63, k = gid >> 6;
    const float4* st4 = (const float4*)states;
    float4 s = st4[k];
    float acc = s.x * W1[col] + s.y * W1[64 + col] + s.z * W1[128 + col] + s.w * W1[192 + col];
    yswz[yswz_idx(k, col)] = f2bf(dinv[k] * acc);
}

// ---------- kernel 3/6: Z_partial[ks] = maskbits(A_hat) @ Y  via bf16 MFMA ----------
// grid 512: mt = bid>>2 (64-row tile), ks = bid&3 (K split of 2048).
// block = 4 waves x 16 rows. BK=128 chunk double-buffered in LDS (2x16KB).
__global__ __launch_bounds__(256, 2) void k_agg(const unsigned short* __restrict__ yswz,
                                                const unsigned int* __restrict__ maskb,
                                                float* __restrict__ zp) {
    __shared__ uint4 smem[2048];  // 32 KB
    int tid = threadIdx.x;
    int wv = tid >> 6, L = tid & 63;
    int bid = blockIdx.x;
    int mt = bid >> 2, ks = bid & 3;
    int n = L & 15, quad = L >> 4;
    int i = mt * 64 + wv * 16 + n;                       // A-operand row (m = lane&15)
    const unsigned int* mrow = maskb + (size_t)i * 256 + ks * 64;
    const uint4* ysrc = (const uint4*)(yswz + (size_t)ks * 131072);
    int boff = n * 64 + ((quad ^ (n & 3)) << 4);         // B-frag byte offset in kblock

    f32x4 acc[4] = {{0,0,0,0},{0,0,0,0},{0,0,0,0},{0,0,0,0}};
    uint4 v0, v1, v2, v3;
    int sidx = wv * 256 + L;

    // prime: issue loads for chunk 0
    {
        const uint4* s = ysrc + sidx;
        v0 = s[0]; v1 = s[64]; v2 = s[128]; v3 = s[192];
    }
    for (int ch = 0; ch < 16; ++ch) {
        // write current chunk's data to its LDS buffer
        uint4* d = smem + (ch & 1) * 1024 + sidx;
        d[0] = v0; d[64] = v1; d[128] = v2; d[192] = v3;
        // issue next chunk's global loads (overlap with compute below)
        if (ch + 1 < 16) {
            const uint4* s = ysrc + (ch + 1) * 1024 + sidx;
            v0 = s[0]; v1 = s[64]; v2 = s[128]; v3 = s[192];
        }
        __syncthreads();
        const char* base = (const char*)(smem + (ch & 1) * 1024);
#pragma unroll
        for (int kb = 0; kb < 4; ++kb) {
            unsigned int w = mrow[ch * 4 + kb];
            unsigned int byte = (w >> (quad * 8)) & 0xffu;
            s16x8 afrag;
#pragma unroll
            for (int t = 0; t < 8; ++t)
                afrag[t] = (short)(((byte >> t) & 1u) ? 0x3F80 : 0);
            const char* kbb = base + kb * 4096;
#pragma unroll
            for (int ct = 0; ct < 4; ++ct) {
                s16x8 bfrag = *(const s16x8*)(kbb + ct * 1024 + boff);
                acc[ct] = __builtin_amdgcn_mfma_f32_16x16x32_bf16(afrag, bfrag, acc[ct], 0, 0, 0);
            }
        }
        __syncthreads();
    }
    // epilogue: D layout col = lane&15, row = quad*4 + reg
    float* zb = zp + (size_t)ks * (NPTS * 64) + (size_t)(mt * 64 + wv * 16) * 64;
#pragma unroll
    for (int ct = 0; ct < 4; ++ct)
#pragma unroll
        for (int r = 0; r < 4; ++r)
            zb[(quad * 4 + r) * 64 + ct * 16 + n] = acc[ct][r];
}

// ---------- kernel 4: h1 = relu(dinv * sum(Zpart) + b1) ----------
__global__ __launch_bounds__(256) void k_h1(const float* __restrict__ zp,
                                            const float* __restrict__ dinv,
                                            const float* __restrict__ b1,
                                            float* __restrict__ h1) {
    int gid = blockIdx.x * 256 + threadIdx.x;
    int col = gid & 63, j = gid >> 6;
    float z = zp[gid] + zp[524288 + gid] + zp[1048576 + gid] + zp[1572864 + gid];
    h1[gid] = fmaxf(dinv[j] * z + b1[col], 0.0f);
}

// ---------- kernel 5: Y2 = dinv * (h1 @ W2), bf16 swizzled ----------
__global__ __launch_bounds__(256) void k_y2(const float* __restrict__ h1,
                                            const float* __restrict__ W2,
                                            const float* __restrict__ dinv,
                                            unsigned short* __restrict__ yswz) {
    __shared__ float w2s[4096];
    int tid = threadIdx.x;
#pragma unroll
    for (int s = 0; s < 16; ++s) w2s[s * 256 + tid] = W2[s * 256 + tid];
    __syncthreads();
    int col = tid & 63;
    int j = blockIdx.x * 4 + (tid >> 6);
    const float* hr = h1 + j * 64;
    float acc = 0.0f;
#pragma unroll
    for (int m = 0; m < 64; ++m) acc = fmaf(hr[m], w2s[m * 64 + col], acc);
    yswz[yswz_idx(j, col)] = f2bf(dinv[j] * acc);
}

// ---------- kernel 7: out[i] = relu(dinv*sum(Zpart2)+b2) . cw + cb ----------
__global__ __launch_bounds__(256) void k_out(const float* __restrict__ zp,
                                             const float* __restrict__ dinv,
                                             const float* __restrict__ b2,
                                             const float* __restrict__ cw,
                                             const float* __restrict__ cb,
                                             float* __restrict__ out) {
    int tid = threadIdx.x;
    int wv = tid >> 6, L = tid & 63;
    int i = blockIdx.x * 4 + wv;
    int idx = i * 64 + L;
    float z = zp[idx] + zp[524288 + idx] + zp[1048576 + idx] + zp[1572864 + idx];
    float h = fmaxf(dinv[i] * z + b2[L], 0.0f);
    float v = h * cw[L];
#pragma unroll
    for (int off = 32; off > 0; off >>= 1) v += __shfl_down(v, off, 64);
    if (L == 0) out[i] = v + cb[0];
}

// ---------- launch ----------
extern "C" void kernel_launch(void* const* d_in, const int* in_sizes, int n_in,
                              void* d_out, int out_size, void* d_ws, size_t ws_size,
                              hipStream_t stream) {
    const float* states = (const float*)d_in[0];
    const float* W1 = (const float*)d_in[1];
    const float* b1 = (const float*)d_in[2];
    const float* W2 = (const float*)d_in[3];
    const float* b2 = (const float*)d_in[4];
    const float* cw = (const float*)d_in[5];
    const float* cb = (const float*)d_in[6];
    float* out = (float*)d_out;
    float* mout = out + NPTS;  // mask floats start after out[8192]

    char* ws = (char*)d_ws;
    float* dinv                 = (float*)(ws);                 // 32 KB
    unsigned long long* maskb   = (unsigned long long*)(ws + 32768);    // 8 MiB
    unsigned short* yb1         = (unsigned short*)(ws + 8421376);      // 1 MiB
    unsigned short* yb2         = (unsigned short*)(ws + 9469952);      // 1 MiB
    float* h1b                  = (float*)(ws + 10518528);              // 2 MiB
    float* zp                   = (float*)(ws + 12615680);              // 8 MiB (4 K-split partials)

    hipLaunchKernelGGL(k_mask, dim3(512), dim3(256), 0, stream, states, mout, maskb, dinv);
    hipLaunchKernelGGL(k_y1,   dim3(2048), dim3(256), 0, stream, states, W1, dinv, yb1);
    hipLaunchKernelGGL(k_agg,  dim3(512), dim3(256), 0, stream, yb1, (const unsigned int*)maskb, zp);
    hipLaunchKernelGGL(k_h1,   dim3(2048), dim3(256), 0, stream, zp, dinv, b1, h1b);
    hipLaunchKernelGGL(k_y2,   dim3(2048), dim3(256), 0, stream, h1b, W2, dinv, yb2);
    hipLaunchKernelGGL(k_agg,  dim3(512), dim3(256), 0, stream, yb2, (const unsigned int*)maskb, zp);
    hipLaunchKernelGGL(k_out,  dim3(2048), dim3(256), 0, stream, zp, dinv, b2, cw, cb, out);
}

// Round 2
// 378.894 us; speedup vs baseline: 1.1893x; 1.1893x over previous
//
#include <hip/hip_runtime.h>
#include <hip/hip_bf16.h>
#include <stdint.h>

#define NPTS 8192
#define KSPLIT 8   // K split for aggregation; zp has KSPLIT partial buffers

typedef float f32x4 __attribute__((ext_vector_type(4)));
typedef short s16x8 __attribute__((ext_vector_type(8)));

// bf16 round-to-nearest-even
__device__ __forceinline__ unsigned short f2bf(float f) {
    unsigned int u = __builtin_bit_cast(unsigned int, f);
    u += 0x7FFFu + ((u >> 16) & 1u);
    return (unsigned short)(u >> 16);
}

// Y is stored in exact MFMA-B-fragment order (16x16x32 bf16):
// frag unit = (kb, ct, lane L=quad*16+n): 8 elements k=kb*32+quad*8+t, col=ct*16+n,
// flat uint4 index = (kb*4 + ct)*64 + L. A wave's (kb,ct) read = contiguous 1KB.

// ---------- kernel 1: mask floats (256 MiB) + packed bits + dinv ----------
// grid 512 x 256. xy pairs staged once in 64KB LDS -> L2 traffic cut 16x.
__global__ __launch_bounds__(256) void k_mask(const float* __restrict__ states,
                                              float* __restrict__ mout,
                                              unsigned long long* __restrict__ maskb,
                                              float* __restrict__ dinv) {
    __shared__ float2 xy[NPTS];  // 64 KB
    int tid = threadIdx.x;
    for (int r = tid; r < NPTS; r += 256) {
        float4 s = ((const float4*)states)[r];
        xy[r] = make_float2(s.x, s.y);
    }
    __syncthreads();
    int wv = tid >> 6, L = tid & 63;
    int rowbase = blockIdx.x * 16 + wv * 4;
    for (int rr = 0; rr < 4; ++rr) {
        int i = rowbase + rr;
        float2 pi = xy[i];
        int deg = 0;
        float* orow = mout + (size_t)i * NPTS;
        unsigned long long* brow = maskb + (size_t)i * 128;
        for (int it = 0; it < 128; ++it) {
            int j = it * 64 + L;
            float2 pj = xy[j];
            float dx = pi.x - pj.x;
            float dy = pi.y - pj.y;
            // must match numpy fp32 (dx*dx)+(dy*dy), no FMA contraction:
            float d2 = __fadd_rn(__fmul_rn(dx, dx), __fmul_rn(dy, dy));
            bool pred = (d2 <= 1.0f);
            orow[j] = pred ? 1.0f : 0.0f;
            unsigned long long b = __ballot(pred);
            if (L == 0) brow[it] = b;
            deg += (int)__popcll(b);
        }
        if (L == 0) dinv[i] = rsqrtf((float)deg);
    }
}

// ---------- kernel 2: Y1 = dinv * (states @ W1), bf16 frag order ----------
// one thread per 16B fragment: grid 256 x 256 = 65536 frags.
__global__ __launch_bounds__(256) void k_y1(const float* __restrict__ states,
                                            const float* __restrict__ W1,
                                            const float* __restrict__ dinv,
                                            uint4* __restrict__ y) {
    int gid = blockIdx.x * 256 + threadIdx.x;
    int L = gid & 63, ct = (gid >> 6) & 3, kb = gid >> 8;
    int n = L & 15, quad = L >> 4;
    int col = ct * 16 + n;
    float w0 = W1[col], w1 = W1[64 + col], w2 = W1[128 + col], w3 = W1[192 + col];
    unsigned short frag[8];
#pragma unroll
    for (int t = 0; t < 8; ++t) {
        int k = kb * 32 + quad * 8 + t;
        float4 s = ((const float4*)states)[k];
        float acc = s.x * w0 + s.y * w1 + s.z * w2 + s.w * w3;
        frag[t] = f2bf(dinv[k] * acc);
    }
    uint4 u;
    u.x = (unsigned)frag[0] | ((unsigned)frag[1] << 16);
    u.y = (unsigned)frag[2] | ((unsigned)frag[3] << 16);
    u.z = (unsigned)frag[4] | ((unsigned)frag[5] << 16);
    u.w = (unsigned)frag[6] | ((unsigned)frag[7] << 16);
    y[gid] = u;
}

// ---------- kernel 3/5: Z_partial[ks] = A_hat-bits @ Y via MFMA, no LDS ----------
// grid 128*KSPLIT blocks x 4 waves. wave = 16 rows x 64 cols, K = 8192/KSPLIT.
// B-frags read straight from L2 (coalesced 1KB per load), register prefetch.
__global__ __launch_bounds__(256, 4) void k_agg(const uint4* __restrict__ y,
                                                const unsigned int* __restrict__ maskb,
                                                float* __restrict__ zp) {
    int tid = threadIdx.x;
    int wv = tid >> 6, L = tid & 63;
    int bid = blockIdx.x;
    int mt = bid >> 3, ks = bid & (KSPLIT - 1);
    int n = L & 15, quad = L >> 4;
    int i = mt * 64 + wv * 16 + n;                        // A row
    const unsigned int* mrow = maskb + (size_t)i * 256 + ks * 32;
    const uint4* yb = y + (size_t)(ks * 32) * 256 + L;    // 32 kb per split, 256 uint4/kb

    f32x4 acc[4] = {{0,0,0,0},{0,0,0,0},{0,0,0,0},{0,0,0,0}};
    uint4 bcur[4];
    unsigned int mw = mrow[0];
#pragma unroll
    for (int ct = 0; ct < 4; ++ct) bcur[ct] = yb[ct * 64];

    for (int kb = 0; kb < 32; ++kb) {
        uint4 bnext[4]; unsigned int mwn = 0;
        if (kb < 31) {
            const uint4* p = yb + (kb + 1) * 256;
#pragma unroll
            for (int ct = 0; ct < 4; ++ct) bnext[ct] = p[ct * 64];
            mwn = mrow[kb + 1];
        }
        unsigned int byte = (mw >> (quad * 8)) & 0xFFu;
        s16x8 a;
#pragma unroll
        for (int t = 0; t < 8; ++t)
            a[t] = (short)(((byte >> t) & 1u) ? 0x3F80 : 0);
#pragma unroll
        for (int ct = 0; ct < 4; ++ct)
            acc[ct] = __builtin_amdgcn_mfma_f32_16x16x32_bf16(
                a, __builtin_bit_cast(s16x8, bcur[ct]), acc[ct], 0, 0, 0);
#pragma unroll
        for (int ct = 0; ct < 4; ++ct) bcur[ct] = bnext[ct];
        mw = mwn;
    }
    // D layout: col = lane&15, row = quad*4 + reg
    float* zb = zp + (size_t)ks * (NPTS * 64) + (size_t)(mt * 64 + wv * 16) * 64;
#pragma unroll
    for (int ct = 0; ct < 4; ++ct)
#pragma unroll
        for (int r = 0; r < 4; ++r)
            zb[(quad * 4 + r) * 64 + ct * 16 + n] = acc[ct][r];
}

// ---------- kernel 4: h1 = relu(dinv*sum(zp)+b1); Y2 = dinv*(h1 @ W2) frag order ----------
// grid 1024 blocks x 256; block = 8 rows (aligned to fragment k-group).
__global__ __launch_bounds__(256) void k_h1y2(const float* __restrict__ zp,
                                              const float* __restrict__ dinv,
                                              const float* __restrict__ b1,
                                              const float* __restrict__ W2,
                                              uint4* __restrict__ y2) {
    __shared__ float w2s[4096];          // 16 KB
    __shared__ float hbuf[8 * 64];       // 2 KB
    __shared__ unsigned short ybuf[8 * 64];  // 1 KB
    int tid = threadIdx.x;
#pragma unroll
    for (int s = 0; s < 16; ++s) w2s[s * 256 + tid] = W2[s * 256 + tid];
    int j0 = blockIdx.x * 8;
#pragma unroll
    for (int e = tid; e < 512; e += 256) {
        int r = e >> 6, c = e & 63;
        int j = j0 + r;
        float z = 0.0f;
#pragma unroll
        for (int s = 0; s < KSPLIT; ++s) z += zp[(size_t)s * (NPTS * 64) + j * 64 + c];
        hbuf[r * 64 + c] = fmaxf(dinv[j] * z + b1[c], 0.0f);
    }
    __syncthreads();
#pragma unroll
    for (int e = tid; e < 512; e += 256) {
        int r = e >> 6, c = e & 63;
        const float* hr = hbuf + r * 64;
        float acc = 0.0f;
#pragma unroll
        for (int m = 0; m < 64; ++m) acc = fmaf(hr[m], w2s[m * 64 + c], acc);
        ybuf[r * 64 + c] = f2bf(dinv[j0 + r] * acc);
    }
    __syncthreads();
    if (tid < 64) {
        int c = tid;
        unsigned short v[8];
#pragma unroll
        for (int r = 0; r < 8; ++r) v[r] = ybuf[r * 64 + c];
        uint4 u;
        u.x = (unsigned)v[0] | ((unsigned)v[1] << 16);
        u.y = (unsigned)v[2] | ((unsigned)v[3] << 16);
        u.z = (unsigned)v[4] | ((unsigned)v[5] << 16);
        u.w = (unsigned)v[6] | ((unsigned)v[7] << 16);
        int kb = j0 >> 5, quad = (j0 >> 3) & 3, ct = c >> 4, nn = c & 15;
        y2[(kb * 4 + ct) * 64 + quad * 16 + nn] = u;
    }
}

// ---------- kernel 6: out[i] = relu(dinv*sum(zp2)+b2) . cw + cb ----------
__global__ __launch_bounds__(256) void k_out(const float* __restrict__ zp,
                                             const float* __restrict__ dinv,
                                             const float* __restrict__ b2,
                                             const float* __restrict__ cw,
                                             const float* __restrict__ cb,
                                             float* __restrict__ out) {
    int tid = threadIdx.x;
    int wv = tid >> 6, L = tid & 63;
    int i = blockIdx.x * 4 + wv;
    int idx = i * 64 + L;
    float z = 0.0f;
#pragma unroll
    for (int s = 0; s < KSPLIT; ++s) z += zp[(size_t)s * (NPTS * 64) + idx];
    float h = fmaxf(dinv[i] * z + b2[L], 0.0f);
    float v = h * cw[L];
#pragma unroll
    for (int off = 32; off > 0; off >>= 1) v += __shfl_down(v, off, 64);
    if (L == 0) out[i] = v + cb[0];
}

// ---------- launch ----------
extern "C" void kernel_launch(void* const* d_in, const int* in_sizes, int n_in,
                              void* d_out, int out_size, void* d_ws, size_t ws_size,
                              hipStream_t stream) {
    const float* states = (const float*)d_in[0];
    const float* W1 = (const float*)d_in[1];
    const float* b1 = (const float*)d_in[2];
    const float* W2 = (const float*)d_in[3];
    const float* b2 = (const float*)d_in[4];
    const float* cw = (const float*)d_in[5];
    const float* cb = (const float*)d_in[6];
    float* out = (float*)d_out;
    float* mout = out + NPTS;  // mask floats follow out[8192]

    char* ws = (char*)d_ws;
    float* dinv               = (float*)(ws);                       // 32 KB
    unsigned long long* maskb = (unsigned long long*)(ws + (1 << 16));      // 8 MiB
    uint4* y1                 = (uint4*)(ws + (1 << 16) + (8 << 20));       // 1 MiB
    uint4* y2                 = (uint4*)(ws + (1 << 16) + (9 << 20));       // 1 MiB
    float* zp                 = (float*)(ws + (1 << 16) + (10 << 20));      // 16 MiB

    hipLaunchKernelGGL(k_mask, dim3(512), dim3(256), 0, stream, states, mout, maskb, dinv);
    hipLaunchKernelGGL(k_y1,   dim3(256), dim3(256), 0, stream, states, W1, dinv, y1);
    hipLaunchKernelGGL(k_agg,  dim3(128 * KSPLIT), dim3(256), 0, stream,
                       y1, (const unsigned int*)maskb, zp);
    hipLaunchKernelGGL(k_h1y2, dim3(1024), dim3(256), 0, stream, zp, dinv, b1, W2, y2);
    hipLaunchKernelGGL(k_agg,  dim3(128 * KSPLIT), dim3(256), 0, stream,
                       y2, (const unsigned int*)maskb, zp);
    hipLaunchKernelGGL(k_out,  dim3(2048), dim3(256), 0, stream, zp, dinv, b2, cw, cb, out);
}

// Round 3
// 370.767 us; speedup vs baseline: 1.2154x; 1.0219x over previous
//
#include <hip/hip_runtime.h>
#include <hip/hip_bf16.h>
#include <stdint.h>

#define NPTS 8192
#define KSPLIT 8   // K split for aggregation; zp has KSPLIT partial buffers

typedef float f32x4 __attribute__((ext_vector_type(4)));
typedef short s16x8 __attribute__((ext_vector_type(8)));

// bf16 round-to-nearest-even
__device__ __forceinline__ unsigned short f2bf(float f) {
    unsigned int u = __builtin_bit_cast(unsigned int, f);
    u += 0x7FFFu + ((u >> 16) & 1u);
    return (unsigned short)(u >> 16);
}

// Y is stored in exact MFMA-B-fragment order (16x16x32 bf16):
// frag unit = (kb, ct, lane L=quad*16+n): 8 elements k=kb*32+quad*8+t, col=ct*16+n,
// flat uint4 index = (kb*4 + ct)*64 + L. A wave's (kb,ct) read = contiguous 1KB.

// ---------- kernel 1: mask floats (256 MiB) + packed bits + dinv ----------
// grid 512 x 256. xy pairs staged once in 64KB LDS; mout stores nontemporal
// (never re-read -> don't pollute L2).
__global__ __launch_bounds__(256) void k_mask(const float* __restrict__ states,
                                              float* __restrict__ mout,
                                              unsigned long long* __restrict__ maskb,
                                              float* __restrict__ dinv) {
    __shared__ float2 xy[NPTS];  // 64 KB
    int tid = threadIdx.x;
    for (int r = tid; r < NPTS; r += 256) {
        float4 s = ((const float4*)states)[r];
        xy[r] = make_float2(s.x, s.y);
    }
    __syncthreads();
    int wv = tid >> 6, L = tid & 63;
    int rowbase = blockIdx.x * 16 + wv * 4;
    for (int rr = 0; rr < 4; ++rr) {
        int i = rowbase + rr;
        float2 pi = xy[i];
        int deg = 0;
        float* orow = mout + (size_t)i * NPTS;
        unsigned long long* brow = maskb + (size_t)i * 128;
        for (int it = 0; it < 128; ++it) {
            int j = it * 64 + L;
            float2 pj = xy[j];
            float dx = pi.x - pj.x;
            float dy = pi.y - pj.y;
            // must match numpy fp32 (dx*dx)+(dy*dy), no FMA contraction:
            float d2 = __fadd_rn(__fmul_rn(dx, dx), __fmul_rn(dy, dy));
            bool pred = (d2 <= 1.0f);
            __builtin_nontemporal_store(pred ? 1.0f : 0.0f, &orow[j]);
            unsigned long long b = __ballot(pred);
            if (L == 0) brow[it] = b;
            deg += (int)__popcll(b);
        }
        if (L == 0) dinv[i] = rsqrtf((float)deg);
    }
}

// ---------- kernel 2: Y1 = dinv * (states @ W1), bf16 frag order ----------
__global__ __launch_bounds__(256) void k_y1(const float* __restrict__ states,
                                            const float* __restrict__ W1,
                                            const float* __restrict__ dinv,
                                            uint4* __restrict__ y) {
    int gid = blockIdx.x * 256 + threadIdx.x;
    int L = gid & 63, ct = (gid >> 6) & 3, kb = gid >> 8;
    int n = L & 15, quad = L >> 4;
    int col = ct * 16 + n;
    float w0 = W1[col], w1 = W1[64 + col], w2 = W1[128 + col], w3 = W1[192 + col];
    unsigned short frag[8];
#pragma unroll
    for (int t = 0; t < 8; ++t) {
        int k = kb * 32 + quad * 8 + t;
        float4 s = ((const float4*)states)[k];
        float acc = s.x * w0 + s.y * w1 + s.z * w2 + s.w * w3;
        frag[t] = f2bf(dinv[k] * acc);
    }
    uint4 u;
    u.x = (unsigned)frag[0] | ((unsigned)frag[1] << 16);
    u.y = (unsigned)frag[2] | ((unsigned)frag[3] << 16);
    u.z = (unsigned)frag[4] | ((unsigned)frag[5] << 16);
    u.w = (unsigned)frag[6] | ((unsigned)frag[7] << 16);
    y[gid] = u;
}

// ---------- kernel 3/5: Z_partial[ks] = A_hat-bits @ Y via MFMA ----------
// 32 rows per wave (2 A-fragments share every B-load -> half the L2 traffic).
// grid = 64 mt x 8 ks = 512 blocks, 4 waves; wave = 32 rows x 64 cols, K=1024.
__global__ __launch_bounds__(256) void k_agg(const uint4* __restrict__ y,
                                             const unsigned int* __restrict__ maskb,
                                             float* __restrict__ zp) {
    int tid = threadIdx.x;
    int wv = tid >> 6, L = tid & 63;
    int bid = blockIdx.x;
    int mt = bid >> 3, ks = bid & (KSPLIT - 1);
    int n = L & 15, quad = L >> 4;
    int i0 = mt * 128 + wv * 32 + n;                       // group-0 A row
    const unsigned int* mrow0 = maskb + (size_t)i0 * 256 + ks * 32;
    const unsigned int* mrow1 = mrow0 + 16 * 256;          // group-1 row (+16)
    const uint4* yb = y + (size_t)(ks * 32) * 256 + L;     // 32 kb per split

    f32x4 acc[2][4] = {{{0,0,0,0},{0,0,0,0},{0,0,0,0},{0,0,0,0}},
                       {{0,0,0,0},{0,0,0,0},{0,0,0,0},{0,0,0,0}}};
    uint4 bcur[4];
    unsigned int mw0 = mrow0[0], mw1 = mrow1[0];
#pragma unroll
    for (int ct = 0; ct < 4; ++ct) bcur[ct] = yb[ct * 64];

    for (int kb = 0; kb < 32; ++kb) {
        uint4 bnext[4]; unsigned int mwn0 = 0, mwn1 = 0;
        if (kb < 31) {
            const uint4* p = yb + (kb + 1) * 256;
#pragma unroll
            for (int ct = 0; ct < 4; ++ct) bnext[ct] = p[ct * 64];
            mwn0 = mrow0[kb + 1];
            mwn1 = mrow1[kb + 1];
        }
        unsigned int byte0 = (mw0 >> (quad * 8)) & 0xFFu;
        unsigned int byte1 = (mw1 >> (quad * 8)) & 0xFFu;
        s16x8 a0, a1;
#pragma unroll
        for (int t = 0; t < 8; ++t) {
            a0[t] = (short)(((byte0 >> t) & 1u) ? 0x3F80 : 0);
            a1[t] = (short)(((byte1 >> t) & 1u) ? 0x3F80 : 0);
        }
#pragma unroll
        for (int ct = 0; ct < 4; ++ct) {
            s16x8 b = __builtin_bit_cast(s16x8, bcur[ct]);
            acc[0][ct] = __builtin_amdgcn_mfma_f32_16x16x32_bf16(a0, b, acc[0][ct], 0, 0, 0);
            acc[1][ct] = __builtin_amdgcn_mfma_f32_16x16x32_bf16(a1, b, acc[1][ct], 0, 0, 0);
        }
#pragma unroll
        for (int ct = 0; ct < 4; ++ct) bcur[ct] = bnext[ct];
        mw0 = mwn0; mw1 = mwn1;
    }
    // D layout: col = lane&15, row = quad*4 + reg
    float* zb = zp + (size_t)ks * (NPTS * 64) + (size_t)(mt * 128 + wv * 32) * 64;
#pragma unroll
    for (int g = 0; g < 2; ++g)
#pragma unroll
        for (int ct = 0; ct < 4; ++ct)
#pragma unroll
            for (int r = 0; r < 4; ++r)
                zb[(g * 16 + quad * 4 + r) * 64 + ct * 16 + n] = acc[g][ct][r];
}

// ---------- kernel 4: h1 = relu(dinv*sum(zp)+b1); Y2 = dinv*(h1 @ W2) frag order ----------
__global__ __launch_bounds__(256) void k_h1y2(const float* __restrict__ zp,
                                              const float* __restrict__ dinv,
                                              const float* __restrict__ b1,
                                              const float* __restrict__ W2,
                                              uint4* __restrict__ y2) {
    __shared__ float w2s[4096];          // 16 KB
    __shared__ float hbuf[8 * 64];       // 2 KB
    __shared__ unsigned short ybuf[8 * 64];  // 1 KB
    int tid = threadIdx.x;
#pragma unroll
    for (int s = 0; s < 16; ++s) w2s[s * 256 + tid] = W2[s * 256 + tid];
    int j0 = blockIdx.x * 8;
#pragma unroll
    for (int e = tid; e < 512; e += 256) {
        int r = e >> 6, c = e & 63;
        int j = j0 + r;
        float z = 0.0f;
#pragma unroll
        for (int s = 0; s < KSPLIT; ++s) z += zp[(size_t)s * (NPTS * 64) + j * 64 + c];
        hbuf[r * 64 + c] = fmaxf(dinv[j] * z + b1[c], 0.0f);
    }
    __syncthreads();
#pragma unroll
    for (int e = tid; e < 512; e += 256) {
        int r = e >> 6, c = e & 63;
        const float* hr = hbuf + r * 64;
        float acc = 0.0f;
#pragma unroll
        for (int m = 0; m < 64; ++m) acc = fmaf(hr[m], w2s[m * 64 + c], acc);
        ybuf[r * 64 + c] = f2bf(dinv[j0 + r] * acc);
    }
    __syncthreads();
    if (tid < 64) {
        int c = tid;
        unsigned short v[8];
#pragma unroll
        for (int r = 0; r < 8; ++r) v[r] = ybuf[r * 64 + c];
        uint4 u;
        u.x = (unsigned)v[0] | ((unsigned)v[1] << 16);
        u.y = (unsigned)v[2] | ((unsigned)v[3] << 16);
        u.z = (unsigned)v[4] | ((unsigned)v[5] << 16);
        u.w = (unsigned)v[6] | ((unsigned)v[7] << 16);
        int kb = j0 >> 5, quad = (j0 >> 3) & 3, ct = c >> 4, nn = c & 15;
        y2[(kb * 4 + ct) * 64 + quad * 16 + nn] = u;
    }
}

// ---------- kernel 6: out[i] = relu(dinv*sum(zp2)+b2) . cw + cb ----------
__global__ __launch_bounds__(256) void k_out(const float* __restrict__ zp,
                                             const float* __restrict__ dinv,
                                             const float* __restrict__ b2,
                                             const float* __restrict__ cw,
                                             const float* __restrict__ cb,
                                             float* __restrict__ out) {
    int tid = threadIdx.x;
    int wv = tid >> 6, L = tid & 63;
    int i = blockIdx.x * 4 + wv;
    int idx = i * 64 + L;
    float z = 0.0f;
#pragma unroll
    for (int s = 0; s < KSPLIT; ++s) z += zp[(size_t)s * (NPTS * 64) + idx];
    float h = fmaxf(dinv[i] * z + b2[L], 0.0f);
    float v = h * cw[L];
#pragma unroll
    for (int off = 32; off > 0; off >>= 1) v += __shfl_down(v, off, 64);
    if (L == 0) out[i] = v + cb[0];
}

// ---------- launch ----------
extern "C" void kernel_launch(void* const* d_in, const int* in_sizes, int n_in,
                              void* d_out, int out_size, void* d_ws, size_t ws_size,
                              hipStream_t stream) {
    const float* states = (const float*)d_in[0];
    const float* W1 = (const float*)d_in[1];
    const float* b1 = (const float*)d_in[2];
    const float* W2 = (const float*)d_in[3];
    const float* b2 = (const float*)d_in[4];
    const float* cw = (const float*)d_in[5];
    const float* cb = (const float*)d_in[6];
    float* out = (float*)d_out;
    float* mout = out + NPTS;  // mask floats follow out[8192]

    char* ws = (char*)d_ws;
    float* dinv               = (float*)(ws);                       // 32 KB
    unsigned long long* maskb = (unsigned long long*)(ws + (1 << 16));      // 8 MiB
    uint4* y1                 = (uint4*)(ws + (1 << 16) + (8 << 20));       // 1 MiB
    uint4* y2                 = (uint4*)(ws + (1 << 16) + (9 << 20));       // 1 MiB
    float* zp                 = (float*)(ws + (1 << 16) + (10 << 20));      // 16 MiB

    hipLaunchKernelGGL(k_mask, dim3(512), dim3(256), 0, stream, states, mout, maskb, dinv);
    hipLaunchKernelGGL(k_y1,   dim3(256), dim3(256), 0, stream, states, W1, dinv, y1);
    hipLaunchKernelGGL(k_agg,  dim3(64 * KSPLIT), dim3(256), 0, stream,
                       y1, (const unsigned int*)maskb, zp);
    hipLaunchKernelGGL(k_h1y2, dim3(1024), dim3(256), 0, stream, zp, dinv, b1, W2, y2);
    hipLaunchKernelGGL(k_agg,  dim3(64 * KSPLIT), dim3(256), 0, stream,
                       y2, (const unsigned int*)maskb, zp);
    hipLaunchKernelGGL(k_out,  dim3(2048), dim3(256), 0, stream, zp, dinv, b2, cw, cb, out);
}